// Round 21
// baseline (251.251 us; speedup 1.0000x reference)
//
#include <hip/hip_runtime.h>

#define DIM 128
constexpr float EPS = 1e-5f;
#define NSHARD 32
#define SHARD (NSHARD * 256)  // floats per layer: 32 shards x (sum[128]+sumsq[128])
#define CPAD 16               // cursor padded to one int per 64B line

typedef _Float16 f16;
typedef __attribute__((ext_vector_type(8))) _Float16 f16x8;
typedef __attribute__((ext_vector_type(4))) float f32x4;

// ---------------- prep: W fp16-transpose (blocks 0..11) + degree count (12..) --------
__global__ __launch_bounds__(256) void k_prep(const int* __restrict__ dst,
                                              int* __restrict__ degi, int E,
                                              const float* __restrict__ W0,
                                              const float* __restrict__ W1,
                                              const float* __restrict__ W2,
                                              f16* __restrict__ wt) {
    if (blockIdx.x < 12) {
        int layer = blockIdx.x >> 2;
        int quarter = blockIdx.x & 3;
        const float* W = layer == 0 ? W0 : (layer == 1 ? W1 : W2);
        f16* hi = wt + (size_t)layer * DIM * DIM;
        for (int idx = quarter * 4096 + threadIdx.x; idx < (quarter + 1) * 4096;
             idx += 256) {
            int k = idx >> 7, c = idx & 127;
            hi[c * DIM + k] = (f16)W[idx];
        }
    } else {
        int e = (blockIdx.x - 12) * 256 + threadIdx.x;
        if (e < E) atomicAdd(&degi[dst[e]], 1);
    }
}

// ---------------- fused scan: block-local scan + decoupled lookback + dinv + cursor --
__global__ __launch_bounds__(256) void k_scan(const int* __restrict__ degi,
                                              int* __restrict__ row_ptr,
                                              float* __restrict__ dinv,
                                              int* __restrict__ cursor,
                                              int* __restrict__ bsum,
                                              int n, int E) {
    __shared__ int ws[4];
    __shared__ int sOff;
    int t = threadIdx.x, lane = t & 63, wv = t >> 6;
    int bid = blockIdx.x;
    int i0 = bid * 1024 + t * 4;
    int v[4];
#pragma unroll
    for (int j = 0; j < 4; ++j) {
        int i = i0 + j;
        v[j] = (i < n) ? degi[i] : 0;
        if (i < n) dinv[i] = rsqrtf((float)v[j] + 1.0f);
    }
    int tsum = v[0] + v[1] + v[2] + v[3];
    int sc = tsum;
#pragma unroll
    for (int off = 1; off < 64; off <<= 1) {
        int u = __shfl_up(sc, off, 64);
        if (lane >= off) sc += u;
    }
    if (lane == 63) ws[wv] = sc;
    __syncthreads();
    int woff = 0;
    for (int j = 0; j < wv; ++j) woff += ws[j];
    int run = woff + sc - tsum;  // exclusive prefix within block

    if (t == 255) atomicExch(&bsum[bid], woff + sc + 1);

    if (wv == 0) {
        int part = 0;
        if (lane < bid) {
            int val;
            do { val = atomicAdd(&bsum[lane], 0); } while (val == 0);
            part = val - 1;
        }
#pragma unroll
        for (int off = 1; off < 64; off <<= 1) part += __shfl_xor(part, off, 64);
        if (lane == 0) sOff = part;
    }
    __syncthreads();
    int soff = sOff;

#pragma unroll
    for (int j = 0; j < 4; ++j) {
        int i = i0 + j;
        if (i < n) {
            row_ptr[i] = run + soff;
            cursor[(size_t)i * CPAD] = run + soff;
        }
        run += v[j];
    }
    if (bid == 0 && t == 0) row_ptr[n] = E;
}

// ---------------- MFMA GEMM body: fp16 A x fp16 W, 64-row tile (3 blocks/CU) ---------
template <bool PRE_BN>
__device__ __forceinline__ void mm_body(
    const float* __restrict__ inF, const f16* __restrict__ inH,
    const f16* __restrict__ wt, const float* __restrict__ dinv,
    const float* __restrict__ stats, const float* __restrict__ g,
    const float* __restrict__ be, float inv_n, f16* __restrict__ out,
    int n, int bid) {
    __shared__ __align__(16) char sA[64 * 256];
    __shared__ float sScale[DIM], sShift[DIM];

    int t = threadIdx.x;
    int w = t >> 6, l = t & 63;
    int row0 = bid * 64;
    if (row0 >= n) return;

    if (PRE_BN) {
        if (t < DIM) {
            float su = 0.f, sq = 0.f;
#pragma unroll
            for (int s = 0; s < NSHARD; ++s) {
                su += stats[s * 256 + t];
                sq += stats[s * 256 + 128 + t];
            }
            float mu = su * inv_n;
            float var = sq * inv_n - mu * mu;
            float sc = rsqrtf(var + EPS) * g[t];
            sScale[t] = sc;
            sShift[t] = be[t] - mu * sc;
        }
    }

    // ---- W fragments ----
    f16x8 bh[2][4];
    {
        int col = w * 32 + (l & 15);
        int ksub = (l >> 4) * 8;
#pragma unroll
        for (int ct = 0; ct < 2; ++ct) {
            int c2 = col + ct * 16;
#pragma unroll
            for (int kt = 0; kt < 4; ++kt)
                bh[ct][kt] = *(const f16x8*)&wt[(size_t)c2 * DIM + kt * 32 + ksub];
        }
    }
    if (PRE_BN) __syncthreads();  // sScale/sShift ready

    // ---- stage A tile (64x128 fp16), XOR-swizzled ----
    {
        int r = t >> 2;
        int row_g = row0 + r;
        if (row_g >= n) row_g = n - 1;
        int cbase = (t & 3) * 32;
#pragma unroll
        for (int o = 0; o < 4; ++o) {
            int c0 = cbase + o * 8;
            f16x8 h8;
            if (PRE_BN) {
                f16x8 v8 = *(const f16x8*)(inH + (size_t)row_g * DIM + c0);
#pragma unroll
                for (int j = 0; j < 8; ++j) {
                    float v = (float)v8[j] * sScale[c0 + j] + sShift[c0 + j];
                    h8[j] = (f16)fmaxf(v, 0.f);
                }
            } else {
                float4 v0 = *(const float4*)(inF + (size_t)row_g * DIM + c0);
                float4 v1 = *(const float4*)(inF + (size_t)row_g * DIM + c0 + 4);
                h8[0] = (f16)v0.x; h8[1] = (f16)v0.y; h8[2] = (f16)v0.z; h8[3] = (f16)v0.w;
                h8[4] = (f16)v1.x; h8[5] = (f16)v1.y; h8[6] = (f16)v1.z; h8[7] = (f16)v1.w;
            }
            int byte = (r * 256 + c0 * 2) ^ ((r & 7) << 4);
            *(f16x8*)(sA + byte) = h8;
        }
    }
    __syncthreads();

    // ---- MFMA: single product ----
    f32x4 acc[4][2];
#pragma unroll
    for (int rt = 0; rt < 4; ++rt)
#pragma unroll
        for (int ct = 0; ct < 2; ++ct) acc[rt][ct] = (f32x4){0.f, 0.f, 0.f, 0.f};

#pragma unroll
    for (int rt = 0; rt < 4; ++rt) {
        int row_l = rt * 16 + (l & 15);
        int kb = (l >> 4) * 16;
        f16x8 a[4];
#pragma unroll
        for (int kt = 0; kt < 4; ++kt) {
            int byte = (row_l * 256 + kt * 64 + kb) ^ ((row_l & 7) << 4);
            a[kt] = *(const f16x8*)(sA + byte);
        }
#pragma unroll
        for (int ct = 0; ct < 2; ++ct) {
            f32x4 c = acc[rt][ct];
#pragma unroll
            for (int kt = 0; kt < 4; ++kt)
                c = __builtin_amdgcn_mfma_f32_16x16x32_f16(a[kt], bh[ct][kt], c, 0, 0, 0);
            acc[rt][ct] = c;
        }
    }

    // ---- epilogue: scale by dinv[row], store fp16 ----
    int colw = w * 32 + (l & 15);
#pragma unroll
    for (int rt = 0; rt < 4; ++rt) {
        int row_l = rt * 16 + ((l >> 4) << 2);
#pragma unroll
        for (int reg = 0; reg < 4; ++reg) {
            int gr = row0 + row_l + reg;
            if (gr >= n) continue;
            float dv = dinv[gr];
#pragma unroll
            for (int ct = 0; ct < 2; ++ct)
                out[(size_t)gr * DIM + colw + ct * 16] = (f16)(acc[rt][ct][reg] * dv);
        }
    }
}

template <bool PRE_BN>
__global__ __launch_bounds__(256) void k_matmul_mfma(
    const float* __restrict__ inF, const f16* __restrict__ inH,
    const f16* __restrict__ wt, const float* __restrict__ dinv,
    const float* __restrict__ stats, const float* __restrict__ g,
    const float* __restrict__ be, float inv_n, f16* __restrict__ out, int n) {
    mm_body<PRE_BN>(inF, inH, wt, dinv, stats, g, be, inv_n, out, n, blockIdx.x);
}

// ---------------- fused: layer-0 matmul (blocks < mmBlocks) + CSR fill (rest) --------
__global__ __launch_bounds__(256) void k_mm0_fill(
    const float* __restrict__ inF, const f16* __restrict__ wt,
    const float* __restrict__ dinv, f16* __restrict__ out, int n, int mmBlocks,
    const int* __restrict__ src, const int* __restrict__ dst,
    int* __restrict__ cursor, int* __restrict__ csr_src, int E) {
    if ((int)blockIdx.x >= mmBlocks) {
        int e = ((int)blockIdx.x - mmBlocks) * 256 + threadIdx.x;
        if (e < E) {
            int d = dst[e];
            int slot = atomicAdd(&cursor[(size_t)d * CPAD], 1);
            csr_src[slot] = src[e];
        }
        return;
    }
    mm_body<false>(inF, nullptr, wt, dinv, nullptr, nullptr, nullptr, 1.0f, out, n,
                   blockIdx.x);
}

// ---------------- fused gather + BN stats (+ pool): 4 waves = 4 nodes/block ----------
template <bool POOL>
__global__ __launch_bounds__(256) void k_gs(const f16* __restrict__ hs,
                                            const int* __restrict__ csr_src,
                                            const int* __restrict__ row_ptr,
                                            const float* __restrict__ dinv,
                                            const float* __restrict__ b,
                                            const int* __restrict__ batch,
                                            f16* __restrict__ agg,
                                            float* __restrict__ stats_part,
                                            float* __restrict__ gsum, int n) {
    __shared__ float sSum[4][DIM];
    __shared__ float sSq[4][DIM];
    __shared__ int sSeg[4];

    int t = threadIdx.x;
    int wv = t >> 6, l = t & 63;
    int node = blockIdx.x * 4 + wv;
    int grp = l >> 4;
    int c8 = (l & 15) * 8;
    bool valid = node < n;

    f16x8 hv = {};
    if (valid && grp == 0) hv = *(const f16x8*)(hs + (size_t)node * DIM + c8);

    float acc[8] = {};
    int beg = 0, end = 0;
    if (valid) {
        beg = row_ptr[node];
        end = row_ptr[node + 1];
    }
    for (int e = beg + grp; e < end; e += 16) {
        bool v1 = e + 4 < end, v2 = e + 8 < end, v3 = e + 12 < end;
        f16x8 a0 = *(const f16x8*)(hs + (size_t)csr_src[e] * DIM + c8);
        f16x8 a1 = {}, a2 = {}, a3 = {};
        if (v1) a1 = *(const f16x8*)(hs + (size_t)csr_src[e + 4] * DIM + c8);
        if (v2) a2 = *(const f16x8*)(hs + (size_t)csr_src[e + 8] * DIM + c8);
        if (v3) a3 = *(const f16x8*)(hs + (size_t)csr_src[e + 12] * DIM + c8);
        f16x8 s = (a0 + a1) + (a2 + a3);  // 8x v_pk_add_f16, 2 roundings
#pragma unroll
        for (int j = 0; j < 8; ++j) acc[j] += (float)s[j];
    }
#pragma unroll
    for (int j = 0; j < 8; ++j) {
        acc[j] += __shfl_xor(acc[j], 16, 64);
        acc[j] += __shfl_xor(acc[j], 32, 64);
    }

    if (grp == 0) {
        if (valid) {
            float dv = dinv[node];
            f32x4 bb0 = *(const f32x4*)(b + c8);
            f32x4 bb1 = *(const f32x4*)(b + c8 + 4);
            float o[8];
#pragma unroll
            for (int j = 0; j < 4; ++j) {
                o[j] = (acc[j] + (float)hv[j]) * dv + bb0[j];
                o[j + 4] = (acc[j + 4] + (float)hv[j + 4]) * dv + bb1[j];
            }
            f16x8 ov;
#pragma unroll
            for (int j = 0; j < 8; ++j) ov[j] = (f16)o[j];
            *(f16x8*)(agg + (size_t)node * DIM + c8) = ov;
            f32x4 s0 = {o[0], o[1], o[2], o[3]}, s1 = {o[4], o[5], o[6], o[7]};
            f32x4 q0 = {o[0]*o[0], o[1]*o[1], o[2]*o[2], o[3]*o[3]};
            f32x4 q1 = {o[4]*o[4], o[5]*o[5], o[6]*o[6], o[7]*o[7]};
            *(f32x4*)&sSum[wv][c8] = s0;
            *(f32x4*)&sSum[wv][c8 + 4] = s1;
            *(f32x4*)&sSq[wv][c8] = q0;
            *(f32x4*)&sSq[wv][c8 + 4] = q1;
            if (POOL && l == 0) sSeg[wv] = batch[node] - batch[0];
        } else {
            f32x4 z = {0.f, 0.f, 0.f, 0.f};
            *(f32x4*)&sSum[wv][c8] = z;
            *(f32x4*)&sSum[wv][c8 + 4] = z;
            *(f32x4*)&sSq[wv][c8] = z;
            *(f32x4*)&sSq[wv][c8 + 4] = z;
            if (POOL && l == 0) sSeg[wv] = -1;
        }
    }
    __syncthreads();

    int shard = (blockIdx.x & (NSHARD - 1)) * 256;
    if (t < 128) {
        float s = sSum[0][t] + sSum[1][t] + sSum[2][t] + sSum[3][t];
        atomicAdd(&stats_part[shard + t], s);
    } else {
        int ch = t - 128;
        float s = sSq[0][ch] + sSq[1][ch] + sSq[2][ch] + sSq[3][ch];
        atomicAdd(&stats_part[shard + 128 + ch], s);
    }

    if (POOL && t < 128) {
        int cur = -1;
        float a = 0.f;
#pragma unroll
        for (int w = 0; w < 4; ++w) {
            int sg = sSeg[w];
            if (sg < 0) continue;
            if (sg != cur) {
                if (cur >= 0) atomicAdd(&gsum[(size_t)cur * DIM + t], a);
                a = 0.f;
                cur = sg;
            }
            a += sSum[w][t];
        }
        if (cur >= 0) atomicAdd(&gsum[(size_t)cur * DIM + t], a);
    }
}

// ---------------- pool finalize: out = mean*scale + shift ----------------
__global__ __launch_bounds__(128) void k_pool_fin(const float* __restrict__ gsum,
                                                  const int* __restrict__ batch,
                                                  const float* __restrict__ stats,
                                                  const float* __restrict__ g,
                                                  const float* __restrict__ be,
                                                  float* __restrict__ out,
                                                  int n, float inv_n) {
    int gseg = blockIdx.x;
    int c = threadIdx.x;
    int b0 = batch[0];
    int target = b0 + gseg;
    int lo = 0, hi = n;
    while (lo < hi) { int mid = (lo + hi) >> 1; if (batch[mid] < target) lo = mid + 1; else hi = mid; }
    int start = lo;
    lo = start; hi = n;
    while (lo < hi) { int mid = (lo + hi) >> 1; if (batch[mid] < target + 1) lo = mid + 1; else hi = mid; }
    int end = lo;
    int cnt = end - start;

    float su = 0.f, sq = 0.f;
#pragma unroll
    for (int s = 0; s < NSHARD; ++s) {
        su += stats[s * 256 + c];
        sq += stats[s * 256 + 128 + c];
    }
    float mu = su * inv_n;
    float var = sq * inv_n - mu * mu;
    float scale = rsqrtf(var + EPS) * g[c];
    float shift = be[c] - mu * scale;
    float o = 0.f;
    if (cnt > 0) o = (gsum[(size_t)gseg * DIM + c] / (float)cnt) * scale + shift;
    out[(size_t)gseg * DIM + c] = o;
}

// ---------------- launch ----------------
extern "C" void kernel_launch(void* const* d_in, const int* in_sizes, int n_in,
                              void* d_out, int out_size, void* d_ws, size_t ws_size,
                              hipStream_t stream) {
    const float* x = (const float*)d_in[0];
    const int* edge_index = (const int*)d_in[1];
    const int* batch = (const int*)d_in[3];
    const float* W1 = (const float*)d_in[4];
    const float* b1 = (const float*)d_in[5];
    const float* g1 = (const float*)d_in[6];
    const float* be1 = (const float*)d_in[7];
    const float* Wm = (const float*)d_in[8];
    const float* bm = (const float*)d_in[9];
    const float* gm = (const float*)d_in[10];
    const float* bem = (const float*)d_in[11];
    const float* W2 = (const float*)d_in[12];
    const float* b2 = (const float*)d_in[13];
    const float* g2 = (const float*)d_in[14];
    const float* be2 = (const float*)d_in[15];

    int n = in_sizes[0] / DIM;
    int E = in_sizes[1] / 2;
    int G = out_size / DIM;

    const int* srcI = edge_index;
    const int* dstI = edge_index + E;

    char* p = (char*)d_ws;
    f16* bufA = (f16*)p;                p += (size_t)n * DIM * 2;   // hs fp16
    f16* bufB = (f16*)p;                p += (size_t)n * DIM * 2;   // agg fp16
    float* dinv = (float*)p;            p += (size_t)n * 4;
    int* row_ptr = (int*)p;             p += (size_t)(n + 1) * 4;
    int* cursor = (int*)p;              p += (size_t)n * CPAD * 4;  // 64B-padded
    int* csr_src = (int*)p;             p += (size_t)E * 4;
    // ---- contiguous zero region ----
    char* zero0 = p;
    int* degi = (int*)p;                p += (size_t)n * 4;
    float* stats3 = (float*)p;          p += 3 * SHARD * 4;
    float* gsum = (float*)p;            p += (size_t)G * DIM * 4;
    int* bsum = (int*)p;                p += 64 * 4;                 // lookback flags
    size_t zero_bytes = (size_t)(p - zero0);
    // ---- W fp16 transposed buffer ----
    f16* wsplit = (f16*)p;              p += (size_t)3 * DIM * DIM * 2;

    float* out = (float*)d_out;
    float inv_n = 1.0f / (float)n;
    int nb = (n + 1023) / 1024;  // <= 64 assumed

    // ---- init + CSR build + W transpose ----
    hipMemsetAsync(zero0, 0, zero_bytes, stream);
    k_prep<<<12 + (E + 255) / 256, 256, 0, stream>>>(dstI, degi, E, W1, Wm, W2, wsplit);
    k_scan<<<nb, 256, 0, stream>>>(degi, row_ptr, dinv, cursor, bsum, n, E);

    struct Layer { const float *b, *g, *be; };
    Layer L[3] = {{b1, g1, be1}, {bm, gm, bem}, {b2, g2, be2}};

    int mmBlocks = (n + 63) / 64;
    int fillBlocks = (E + 255) / 256;
    int gsBlocks = (n + 3) / 4;

    // layer 0 matmul fused with CSR fill (independent work, one dispatch)
    k_mm0_fill<<<mmBlocks + fillBlocks, 256, 0, stream>>>(
        x, wsplit, dinv, bufA, n, mmBlocks, srcI, dstI, cursor, csr_src, E);
    k_gs<false><<<gsBlocks, 256, 0, stream>>>(bufA, csr_src, row_ptr, dinv,
                                              L[0].b, batch, bufB, stats3,
                                              nullptr, n);

    for (int l = 1; l < 3; ++l) {
        const f16* wl = wsplit + (size_t)l * DIM * DIM;
        float* stats_l = stats3 + l * SHARD;
        k_matmul_mfma<true><<<mmBlocks, 256, 0, stream>>>(
            nullptr, bufB, wl, dinv, stats3 + (l - 1) * SHARD,
            L[l - 1].g, L[l - 1].be, inv_n, bufA, n);
        if (l < 2)
            k_gs<false><<<gsBlocks, 256, 0, stream>>>(bufA, csr_src, row_ptr, dinv,
                                                      L[l].b, batch, bufB, stats_l,
                                                      nullptr, n);
        else
            k_gs<true><<<gsBlocks, 256, 0, stream>>>(bufA, csr_src, row_ptr, dinv,
                                                     L[l].b, batch, bufB, stats_l,
                                                     gsum, n);
    }

    // pool finalize: mean -> final BN affine
    k_pool_fin<<<G, 128, 0, stream>>>(gsum, batch, stats3 + 2 * SHARD, g2, be2,
                                      out, n, inv_n);
}

// Round 22
// 234.804 us; speedup vs baseline: 1.0700x; 1.0700x over previous
//
#include <hip/hip_runtime.h>

#define DIM 128
constexpr float EPS = 1e-5f;
#define NSHARD 32
#define SHARD (NSHARD * 256)  // floats per layer: 32 shards x (sum[128]+sumsq[128])
#define CPAD 16               // cursor padded to one int per 64B line

typedef _Float16 f16;
typedef __attribute__((ext_vector_type(8))) _Float16 f16x8;
typedef __attribute__((ext_vector_type(4))) float f32x4;

// ---------------- prep: W fp16-transpose (blocks 0..11) + degree count (12..) --------
__global__ __launch_bounds__(256) void k_prep(const int* __restrict__ dst,
                                              int* __restrict__ degi, int E,
                                              const float* __restrict__ W0,
                                              const float* __restrict__ W1,
                                              const float* __restrict__ W2,
                                              f16* __restrict__ wt) {
    if (blockIdx.x < 12) {
        int layer = blockIdx.x >> 2;
        int quarter = blockIdx.x & 3;
        const float* W = layer == 0 ? W0 : (layer == 1 ? W1 : W2);
        f16* hi = wt + (size_t)layer * DIM * DIM;
        for (int idx = quarter * 4096 + threadIdx.x; idx < (quarter + 1) * 4096;
             idx += 256) {
            int k = idx >> 7, c = idx & 127;
            hi[c * DIM + k] = (f16)W[idx];
        }
    } else {
        int e = (blockIdx.x - 12) * 256 + threadIdx.x;
        if (e < E) atomicAdd(&degi[dst[e]], 1);
    }
}

// ---------------- fused scan: block-local scan + decoupled lookback + dinv + cursor --
__global__ __launch_bounds__(256) void k_scan(const int* __restrict__ degi,
                                              int* __restrict__ row_ptr,
                                              float* __restrict__ dinv,
                                              int* __restrict__ cursor,
                                              int* __restrict__ bsum,
                                              int n, int E) {
    __shared__ int ws[4];
    __shared__ int sOff;
    int t = threadIdx.x, lane = t & 63, wv = t >> 6;
    int bid = blockIdx.x;
    int i0 = bid * 1024 + t * 4;
    int v[4];
#pragma unroll
    for (int j = 0; j < 4; ++j) {
        int i = i0 + j;
        v[j] = (i < n) ? degi[i] : 0;
        if (i < n) dinv[i] = rsqrtf((float)v[j] + 1.0f);
    }
    int tsum = v[0] + v[1] + v[2] + v[3];
    int sc = tsum;
#pragma unroll
    for (int off = 1; off < 64; off <<= 1) {
        int u = __shfl_up(sc, off, 64);
        if (lane >= off) sc += u;
    }
    if (lane == 63) ws[wv] = sc;
    __syncthreads();
    int woff = 0;
    for (int j = 0; j < wv; ++j) woff += ws[j];
    int run = woff + sc - tsum;  // exclusive prefix within block

    if (t == 255) atomicExch(&bsum[bid], woff + sc + 1);

    if (wv == 0) {
        int part = 0;
        if (lane < bid) {
            int val;
            do { val = atomicAdd(&bsum[lane], 0); } while (val == 0);
            part = val - 1;
        }
#pragma unroll
        for (int off = 1; off < 64; off <<= 1) part += __shfl_xor(part, off, 64);
        if (lane == 0) sOff = part;
    }
    __syncthreads();
    int soff = sOff;

#pragma unroll
    for (int j = 0; j < 4; ++j) {
        int i = i0 + j;
        if (i < n) {
            row_ptr[i] = run + soff;
            cursor[(size_t)i * CPAD] = run + soff;
        }
        run += v[j];
    }
    if (bid == 0 && t == 0) row_ptr[n] = E;
}

// ---------------- MFMA GEMM body: fp16 A x fp16 W, 128-row block (2 x 64 halves) -----
template <bool PRE_BN>
__device__ __forceinline__ void mm_body(
    const float* __restrict__ inF, const f16* __restrict__ inH,
    const f16* __restrict__ wt, const float* __restrict__ dinv,
    const float* __restrict__ stats, const float* __restrict__ g,
    const float* __restrict__ be, float inv_n, f16* __restrict__ out,
    int n, int bid) {
    __shared__ __align__(16) char sA[64 * 256];
    __shared__ float sScale[DIM], sShift[DIM];

    int t = threadIdx.x;
    int w = t >> 6, l = t & 63;

    if (PRE_BN) {
        if (t < DIM) {
            float su = 0.f, sq = 0.f;
#pragma unroll
            for (int s = 0; s < NSHARD; ++s) {
                su += stats[s * 256 + t];
                sq += stats[s * 256 + 128 + t];
            }
            float mu = su * inv_n;
            float var = sq * inv_n - mu * mu;
            float sc = rsqrtf(var + EPS) * g[t];
            sScale[t] = sc;
            sShift[t] = be[t] - mu * sc;
        }
        __syncthreads();
    }

    // ---- W fragments, loaded once per block (reused by both halves) ----
    f16x8 bh[2][4];
    {
        int col = w * 32 + (l & 15);
        int ksub = (l >> 4) * 8;
#pragma unroll
        for (int ct = 0; ct < 2; ++ct) {
            int c2 = col + ct * 16;
#pragma unroll
            for (int kt = 0; kt < 4; ++kt)
                bh[ct][kt] = *(const f16x8*)&wt[(size_t)c2 * DIM + kt * 32 + ksub];
        }
    }

#pragma unroll
    for (int half = 0; half < 2; ++half) {
        int row0 = bid * 128 + half * 64;
        if (row0 >= n) break;
        if (half == 1) __syncthreads();  // all reads of sA (half 0) done

        // ---- stage A tile (64x128 fp16), XOR-swizzled ----
        {
            int r = t >> 2;
            int row_g = row0 + r;
            if (row_g >= n) row_g = n - 1;
            int cbase = (t & 3) * 32;
#pragma unroll
            for (int o = 0; o < 4; ++o) {
                int c0 = cbase + o * 8;
                f16x8 h8;
                if (PRE_BN) {
                    f16x8 v8 = *(const f16x8*)(inH + (size_t)row_g * DIM + c0);
#pragma unroll
                    for (int j = 0; j < 8; ++j) {
                        float v = (float)v8[j] * sScale[c0 + j] + sShift[c0 + j];
                        h8[j] = (f16)fmaxf(v, 0.f);
                    }
                } else {
                    float4 v0 = *(const float4*)(inF + (size_t)row_g * DIM + c0);
                    float4 v1 = *(const float4*)(inF + (size_t)row_g * DIM + c0 + 4);
                    h8[0] = (f16)v0.x; h8[1] = (f16)v0.y; h8[2] = (f16)v0.z; h8[3] = (f16)v0.w;
                    h8[4] = (f16)v1.x; h8[5] = (f16)v1.y; h8[6] = (f16)v1.z; h8[7] = (f16)v1.w;
                }
                int byte = (r * 256 + c0 * 2) ^ ((r & 7) << 4);
                *(f16x8*)(sA + byte) = h8;
            }
        }
        __syncthreads();

        // ---- MFMA: single product ----
        f32x4 acc[4][2];
#pragma unroll
        for (int rt = 0; rt < 4; ++rt)
#pragma unroll
            for (int ct = 0; ct < 2; ++ct) acc[rt][ct] = (f32x4){0.f, 0.f, 0.f, 0.f};

#pragma unroll
        for (int rt = 0; rt < 4; ++rt) {
            int row_l = rt * 16 + (l & 15);
            int kb = (l >> 4) * 16;
            f16x8 a[4];
#pragma unroll
            for (int kt = 0; kt < 4; ++kt) {
                int byte = (row_l * 256 + kt * 64 + kb) ^ ((row_l & 7) << 4);
                a[kt] = *(const f16x8*)(sA + byte);
            }
#pragma unroll
            for (int ct = 0; ct < 2; ++ct) {
                f32x4 c = acc[rt][ct];
#pragma unroll
                for (int kt = 0; kt < 4; ++kt)
                    c = __builtin_amdgcn_mfma_f32_16x16x32_f16(a[kt], bh[ct][kt], c, 0, 0, 0);
                acc[rt][ct] = c;
            }
        }

        // ---- epilogue: scale by dinv[row], store fp16 ----
        int colw = w * 32 + (l & 15);
#pragma unroll
        for (int rt = 0; rt < 4; ++rt) {
            int row_l = rt * 16 + ((l >> 4) << 2);
#pragma unroll
            for (int reg = 0; reg < 4; ++reg) {
                int gr = row0 + row_l + reg;
                if (gr >= n) continue;
                float dv = dinv[gr];
#pragma unroll
                for (int ct = 0; ct < 2; ++ct)
                    out[(size_t)gr * DIM + colw + ct * 16] = (f16)(acc[rt][ct][reg] * dv);
            }
        }
    }
}

template <bool PRE_BN>
__global__ __launch_bounds__(256) void k_matmul_mfma(
    const float* __restrict__ inF, const f16* __restrict__ inH,
    const f16* __restrict__ wt, const float* __restrict__ dinv,
    const float* __restrict__ stats, const float* __restrict__ g,
    const float* __restrict__ be, float inv_n, f16* __restrict__ out, int n) {
    mm_body<PRE_BN>(inF, inH, wt, dinv, stats, g, be, inv_n, out, n, blockIdx.x);
}

// ---------------- fused: layer-0 matmul (blocks < mmBlocks) + CSR fill (rest) --------
// fill: 1 edge/thread (max wave count); cursor padded (64B line per counter).
__global__ __launch_bounds__(256) void k_mm0_fill(
    const float* __restrict__ inF, const f16* __restrict__ wt,
    const float* __restrict__ dinv, f16* __restrict__ out, int n, int mmBlocks,
    const int* __restrict__ src, const int* __restrict__ dst,
    int* __restrict__ cursor, int* __restrict__ csr_src, int E) {
    if ((int)blockIdx.x >= mmBlocks) {
        int e = ((int)blockIdx.x - mmBlocks) * 256 + threadIdx.x;
        if (e < E) {
            int d = dst[e];
            int slot = atomicAdd(&cursor[(size_t)d * CPAD], 1);
            csr_src[slot] = src[e];
        }
        return;
    }
    mm_body<false>(inF, nullptr, wt, dinv, nullptr, nullptr, nullptr, 1.0f, out, n,
                   blockIdx.x);
}

// ---------------- fused gather + BN stats (+ pool): 4 waves = 4 nodes/block ----------
template <bool POOL>
__global__ __launch_bounds__(256) void k_gs(const f16* __restrict__ hs,
                                            const int* __restrict__ csr_src,
                                            const int* __restrict__ row_ptr,
                                            const float* __restrict__ dinv,
                                            const float* __restrict__ b,
                                            const int* __restrict__ batch,
                                            f16* __restrict__ agg,
                                            float* __restrict__ stats_part,
                                            float* __restrict__ gsum, int n) {
    __shared__ float sSum[4][DIM];
    __shared__ float sSq[4][DIM];
    __shared__ int sSeg[4];

    int t = threadIdx.x;
    int wv = t >> 6, l = t & 63;
    int node = blockIdx.x * 4 + wv;
    int grp = l >> 4;
    int c8 = (l & 15) * 8;
    bool valid = node < n;

    f16x8 hv = {};
    if (valid && grp == 0) hv = *(const f16x8*)(hs + (size_t)node * DIM + c8);

    float acc[8] = {};
    int beg = 0, end = 0;
    if (valid) {
        beg = row_ptr[node];
        end = row_ptr[node + 1];
    }
    for (int e = beg + grp; e < end; e += 16) {
        bool v1 = e + 4 < end, v2 = e + 8 < end, v3 = e + 12 < end;
        f16x8 a0 = *(const f16x8*)(hs + (size_t)csr_src[e] * DIM + c8);
        f16x8 a1 = {}, a2 = {}, a3 = {};
        if (v1) a1 = *(const f16x8*)(hs + (size_t)csr_src[e + 4] * DIM + c8);
        if (v2) a2 = *(const f16x8*)(hs + (size_t)csr_src[e + 8] * DIM + c8);
        if (v3) a3 = *(const f16x8*)(hs + (size_t)csr_src[e + 12] * DIM + c8);
        f16x8 s = (a0 + a1) + (a2 + a3);  // 8x v_pk_add_f16, 2 roundings
#pragma unroll
        for (int j = 0; j < 8; ++j) acc[j] += (float)s[j];
    }
#pragma unroll
    for (int j = 0; j < 8; ++j) {
        acc[j] += __shfl_xor(acc[j], 16, 64);
        acc[j] += __shfl_xor(acc[j], 32, 64);
    }

    if (grp == 0) {
        if (valid) {
            float dv = dinv[node];
            f32x4 bb0 = *(const f32x4*)(b + c8);
            f32x4 bb1 = *(const f32x4*)(b + c8 + 4);
            float o[8];
#pragma unroll
            for (int j = 0; j < 4; ++j) {
                o[j] = (acc[j] + (float)hv[j]) * dv + bb0[j];
                o[j + 4] = (acc[j + 4] + (float)hv[j + 4]) * dv + bb1[j];
            }
            f16x8 ov;
#pragma unroll
            for (int j = 0; j < 8; ++j) ov[j] = (f16)o[j];
            *(f16x8*)(agg + (size_t)node * DIM + c8) = ov;
            f32x4 s0 = {o[0], o[1], o[2], o[3]}, s1 = {o[4], o[5], o[6], o[7]};
            f32x4 q0 = {o[0]*o[0], o[1]*o[1], o[2]*o[2], o[3]*o[3]};
            f32x4 q1 = {o[4]*o[4], o[5]*o[5], o[6]*o[6], o[7]*o[7]};
            *(f32x4*)&sSum[wv][c8] = s0;
            *(f32x4*)&sSum[wv][c8 + 4] = s1;
            *(f32x4*)&sSq[wv][c8] = q0;
            *(f32x4*)&sSq[wv][c8 + 4] = q1;
            if (POOL && l == 0) sSeg[wv] = batch[node] - batch[0];
        } else {
            f32x4 z = {0.f, 0.f, 0.f, 0.f};
            *(f32x4*)&sSum[wv][c8] = z;
            *(f32x4*)&sSum[wv][c8 + 4] = z;
            *(f32x4*)&sSq[wv][c8] = z;
            *(f32x4*)&sSq[wv][c8 + 4] = z;
            if (POOL && l == 0) sSeg[wv] = -1;
        }
    }
    __syncthreads();

    int shard = (blockIdx.x & (NSHARD - 1)) * 256;
    if (t < 128) {
        float s = sSum[0][t] + sSum[1][t] + sSum[2][t] + sSum[3][t];
        atomicAdd(&stats_part[shard + t], s);
    } else {
        int ch = t - 128;
        float s = sSq[0][ch] + sSq[1][ch] + sSq[2][ch] + sSq[3][ch];
        atomicAdd(&stats_part[shard + 128 + ch], s);
    }

    if (POOL && t < 128) {
        int cur = -1;
        float a = 0.f;
#pragma unroll
        for (int w = 0; w < 4; ++w) {
            int sg = sSeg[w];
            if (sg < 0) continue;
            if (sg != cur) {
                if (cur >= 0) atomicAdd(&gsum[(size_t)cur * DIM + t], a);
                a = 0.f;
                cur = sg;
            }
            a += sSum[w][t];
        }
        if (cur >= 0) atomicAdd(&gsum[(size_t)cur * DIM + t], a);
    }
}

// ---------------- pool finalize: out = mean*scale + shift ----------------
__global__ __launch_bounds__(128) void k_pool_fin(const float* __restrict__ gsum,
                                                  const int* __restrict__ batch,
                                                  const float* __restrict__ stats,
                                                  const float* __restrict__ g,
                                                  const float* __restrict__ be,
                                                  float* __restrict__ out,
                                                  int n, float inv_n) {
    int gseg = blockIdx.x;
    int c = threadIdx.x;
    int b0 = batch[0];
    int target = b0 + gseg;
    int lo = 0, hi = n;
    while (lo < hi) { int mid = (lo + hi) >> 1; if (batch[mid] < target) lo = mid + 1; else hi = mid; }
    int start = lo;
    lo = start; hi = n;
    while (lo < hi) { int mid = (lo + hi) >> 1; if (batch[mid] < target + 1) lo = mid + 1; else hi = mid; }
    int end = lo;
    int cnt = end - start;

    float su = 0.f, sq = 0.f;
#pragma unroll
    for (int s = 0; s < NSHARD; ++s) {
        su += stats[s * 256 + c];
        sq += stats[s * 256 + 128 + c];
    }
    float mu = su * inv_n;
    float var = sq * inv_n - mu * mu;
    float scale = rsqrtf(var + EPS) * g[c];
    float shift = be[c] - mu * scale;
    float o = 0.f;
    if (cnt > 0) o = (gsum[(size_t)gseg * DIM + c] / (float)cnt) * scale + shift;
    out[(size_t)gseg * DIM + c] = o;
}

// ---------------- launch ----------------
extern "C" void kernel_launch(void* const* d_in, const int* in_sizes, int n_in,
                              void* d_out, int out_size, void* d_ws, size_t ws_size,
                              hipStream_t stream) {
    const float* x = (const float*)d_in[0];
    const int* edge_index = (const int*)d_in[1];
    const int* batch = (const int*)d_in[3];
    const float* W1 = (const float*)d_in[4];
    const float* b1 = (const float*)d_in[5];
    const float* g1 = (const float*)d_in[6];
    const float* be1 = (const float*)d_in[7];
    const float* Wm = (const float*)d_in[8];
    const float* bm = (const float*)d_in[9];
    const float* gm = (const float*)d_in[10];
    const float* bem = (const float*)d_in[11];
    const float* W2 = (const float*)d_in[12];
    const float* b2 = (const float*)d_in[13];
    const float* g2 = (const float*)d_in[14];
    const float* be2 = (const float*)d_in[15];

    int n = in_sizes[0] / DIM;
    int E = in_sizes[1] / 2;
    int G = out_size / DIM;

    const int* srcI = edge_index;
    const int* dstI = edge_index + E;

    char* p = (char*)d_ws;
    f16* bufA = (f16*)p;                p += (size_t)n * DIM * 2;   // hs fp16
    f16* bufB = (f16*)p;                p += (size_t)n * DIM * 2;   // agg fp16
    float* dinv = (float*)p;            p += (size_t)n * 4;
    int* row_ptr = (int*)p;             p += (size_t)(n + 1) * 4;
    int* cursor = (int*)p;              p += (size_t)n * CPAD * 4;  // 64B-padded
    int* csr_src = (int*)p;             p += (size_t)E * 4;
    // ---- contiguous zero region ----
    char* zero0 = p;
    int* degi = (int*)p;                p += (size_t)n * 4;
    float* stats3 = (float*)p;          p += 3 * SHARD * 4;
    float* gsum = (float*)p;            p += (size_t)G * DIM * 4;
    int* bsum = (int*)p;                p += 64 * 4;                 // lookback flags
    size_t zero_bytes = (size_t)(p - zero0);
    // ---- W fp16 transposed buffer ----
    f16* wsplit = (f16*)p;              p += (size_t)3 * DIM * DIM * 2;

    float* out = (float*)d_out;
    float inv_n = 1.0f / (float)n;
    int nb = (n + 1023) / 1024;  // <= 64 assumed

    // ---- init + CSR build + W transpose ----
    hipMemsetAsync(zero0, 0, zero_bytes, stream);
    k_prep<<<12 + (E + 255) / 256, 256, 0, stream>>>(dstI, degi, E, W1, Wm, W2, wsplit);
    k_scan<<<nb, 256, 0, stream>>>(degi, row_ptr, dinv, cursor, bsum, n, E);

    struct Layer { const float *b, *g, *be; };
    Layer L[3] = {{b1, g1, be1}, {bm, gm, bem}, {b2, g2, be2}};

    int mmBlocks = (n + 127) / 128;
    int fillBlocks = (E + 255) / 256;
    int gsBlocks = (n + 3) / 4;

    // layer 0 matmul fused with CSR fill (independent work, one dispatch)
    k_mm0_fill<<<mmBlocks + fillBlocks, 256, 0, stream>>>(
        x, wsplit, dinv, bufA, n, mmBlocks, srcI, dstI, cursor, csr_src, E);
    k_gs<false><<<gsBlocks, 256, 0, stream>>>(bufA, csr_src, row_ptr, dinv,
                                              L[0].b, batch, bufB, stats3,
                                              nullptr, n);

    for (int l = 1; l < 3; ++l) {
        const f16* wl = wsplit + (size_t)l * DIM * DIM;
        float* stats_l = stats3 + l * SHARD;
        k_matmul_mfma<true><<<mmBlocks, 256, 0, stream>>>(
            nullptr, bufB, wl, dinv, stats3 + (l - 1) * SHARD,
            L[l - 1].g, L[l - 1].be, inv_n, bufA, n);
        if (l < 2)
            k_gs<false><<<gsBlocks, 256, 0, stream>>>(bufA, csr_src, row_ptr, dinv,
                                                      L[l].b, batch, bufB, stats_l,
                                                      nullptr, n);
        else
            k_gs<true><<<gsBlocks, 256, 0, stream>>>(bufA, csr_src, row_ptr, dinv,
                                                     L[l].b, batch, bufB, stats_l,
                                                     gsum, n);
    }

    // pool finalize: mean -> final BN affine
    k_pool_fin<<<G, 128, 0, stream>>>(gsum, batch, stats3 + 2 * SHARD, g2, be2,
                                      out, n, inv_n);
}